// Round 1
// baseline (4530.028 us; speedup 1.0000x reference)
//
#include <hip/hip_runtime.h>
#include <math.h>

#define S 2048
#define MARGIN 0.7f
#define ITERS 500

// ---------------------------------------------------------------------------
// init: log-marginals, zero accumulators
// ---------------------------------------------------------------------------
__global__ __launch_bounds__(256) void init_marg_k(const float* __restrict__ qa,
                                                   const float* __restrict__ ta,
                                                   float* __restrict__ lmu,
                                                   float* __restrict__ lnu,
                                                   float* __restrict__ vt,
                                                   float* __restrict__ dist2) {
  int i = blockIdx.x * 256 + threadIdx.x;
  lmu[i] = __logf(qa[i]);
  lnu[i] = __logf(ta[i]);
  vt[i] = 0.f;     // will accumulate y2 (vt init = v0 + y2 = y2 since v0 = 0)
  dist2[i] = 0.f;
}

// vt[j] += sum_d TF[d,j]^2   (8 j-blocks x 8 d-chunks, atomic combine)
__global__ __launch_bounds__(256) void colsumsq_k(const float* __restrict__ TF,
                                                  float* __restrict__ vt) {
  int jb = blockIdx.x & 7, dc = blockIdx.x >> 3;
  int j = jb * 256 + threadIdx.x;
  int d0 = dc * 256;
  float acc = 0.f;
  for (int d = d0; d < d0 + 256; ++d) {
    float v = TF[d * S + j];
    acc = fmaf(v, v, acc);
  }
  atomicAdd(&vt[j], acc);
}

// ---------------------------------------------------------------------------
// C[i,j] = alpha * sum_k A[k*S+i] * B[k*S+j]   (128x128 tile, BK=16, 8x8/thread)
// ---------------------------------------------------------------------------
__global__ __launch_bounds__(256) void gemm_tn_k(const float* __restrict__ A,
                                                 const float* __restrict__ B,
                                                 float* __restrict__ C, float alpha) {
  __shared__ float As[16][128];
  __shared__ float Bs[16][128];
  int t = threadIdx.x;
  int i0 = blockIdx.y * 128, j0 = blockIdx.x * 128;
  int tx = t & 15, ty = t >> 4;
  float acc[8][8];
#pragma unroll
  for (int r = 0; r < 8; ++r)
#pragma unroll
    for (int c = 0; c < 8; ++c) acc[r][c] = 0.f;

  int e = t * 4;
  int dd0 = e >> 7, ii = e & 127;
  int dd1 = dd0 + 8;
  for (int k0 = 0; k0 < S; k0 += 16) {
    float4 a0 = *(const float4*)&A[(k0 + dd0) * S + i0 + ii];
    float4 b0 = *(const float4*)&B[(k0 + dd0) * S + j0 + ii];
    float4 a1 = *(const float4*)&A[(k0 + dd1) * S + i0 + ii];
    float4 b1 = *(const float4*)&B[(k0 + dd1) * S + j0 + ii];
    __syncthreads();
    *(float4*)&As[dd0][ii] = a0; *(float4*)&Bs[dd0][ii] = b0;
    *(float4*)&As[dd1][ii] = a1; *(float4*)&Bs[dd1][ii] = b1;
    __syncthreads();
#pragma unroll
    for (int kk = 0; kk < 16; ++kk) {
      float a[8], b[8];
      *(float4*)&a[0] = *(const float4*)&As[kk][ty * 8];
      *(float4*)&a[4] = *(const float4*)&As[kk][ty * 8 + 4];
      *(float4*)&b[0] = *(const float4*)&Bs[kk][tx * 4];
      *(float4*)&b[4] = *(const float4*)&Bs[kk][64 + tx * 4];
#pragma unroll
      for (int r = 0; r < 8; ++r)
#pragma unroll
        for (int c = 0; c < 8; ++c) acc[r][c] = fmaf(a[r], b[c], acc[r][c]);
    }
  }
#pragma unroll
  for (int r = 0; r < 8; ++r) {
    int i = i0 + ty * 8 + r;
    float4 o0 = make_float4(acc[r][0] * alpha, acc[r][1] * alpha, acc[r][2] * alpha, acc[r][3] * alpha);
    float4 o1 = make_float4(acc[r][4] * alpha, acc[r][5] * alpha, acc[r][6] * alpha, acc[r][7] * alpha);
    *(float4*)&C[i * S + j0 + tx * 4] = o0;
    *(float4*)&C[i * S + j0 + 64 + tx * 4] = o1;
  }
}

// ---------------------------------------------------------------------------
// out[j*S+i] = in[i*S+j]  (64x64 LDS tiles)
// ---------------------------------------------------------------------------
__global__ __launch_bounds__(256) void transpose_k(const float* __restrict__ in,
                                                   float* __restrict__ out) {
  __shared__ float tile[64][65];
  int i0 = blockIdx.y * 64, j0 = blockIdx.x * 64;
  int tx = threadIdx.x & 63, ty = threadIdx.x >> 6;  // ty 0..3
#pragma unroll
  for (int r = 0; r < 16; ++r) {
    int row = r * 4 + ty;
    tile[row][tx] = in[(i0 + row) * S + j0 + tx];
  }
  __syncthreads();
#pragma unroll
  for (int r = 0; r < 16; ++r) {
    int row = r * 4 + ty;
    out[(j0 + row) * S + i0 + tx] = tile[tx][row];
  }
}

// ---------------------------------------------------------------------------
// outPot[r] = logMarg[r] - LSE_c( G[r*S+c] + inPot[c] )
// one wave per row; row held in registers (exact two-sweep LSE)
// ---------------------------------------------------------------------------
__global__ __launch_bounds__(256) void lse_update_k(const float* __restrict__ G,
                                                    const float* __restrict__ inPot,
                                                    const float* __restrict__ logMarg,
                                                    float* __restrict__ outPot) {
  int wave = threadIdx.x >> 6, lane = threadIdx.x & 63;
  int row = blockIdx.x * 4 + wave;
  const float* g = G + row * S;
  float4 tv[8];
  float mx = -3.4e38f;
#pragma unroll
  for (int c = 0; c < 8; ++c) {
    int idx = c * 256 + lane * 4;
    float4 gv = *(const float4*)&g[idx];
    float4 pv = *(const float4*)&inPot[idx];
    float4 tt = make_float4(gv.x + pv.x, gv.y + pv.y, gv.z + pv.z, gv.w + pv.w);
    tv[c] = tt;
    mx = fmaxf(mx, fmaxf(fmaxf(tt.x, tt.y), fmaxf(tt.z, tt.w)));
  }
#pragma unroll
  for (int off = 32; off; off >>= 1) mx = fmaxf(mx, __shfl_xor(mx, off));
  float s = 0.f;
#pragma unroll
  for (int c = 0; c < 8; ++c) {
    s += __expf(tv[c].x - mx) + __expf(tv[c].y - mx) +
         __expf(tv[c].z - mx) + __expf(tv[c].w - mx);
  }
#pragma unroll
  for (int off = 32; off; off >>= 1) s += __shfl_xor(s, off);
  if (lane == 0) outPot[row] = logMarg[row] - (mx + __logf(s));
}

// ---------------------------------------------------------------------------
// RT[d,i] = sum_j TF[d,j] * exp( GpT[j*S+i] + ut[i] + vt[j] )
// (C = A * P^T with P^T generated on the fly into LDS; 128x128 tile, BK=16)
// ---------------------------------------------------------------------------
__global__ __launch_bounds__(256) void rt_gemm_k(const float* __restrict__ TF,
                                                 const float* __restrict__ GpT,
                                                 const float* __restrict__ ut,
                                                 const float* __restrict__ vt,
                                                 float* __restrict__ RT) {
  __shared__ float As[16][128];  // As[kk][dd] = TF[(d0+dd)*S + k0+kk]
  __shared__ float Bs[16][128];  // Bs[kk][ii] = P^T[k0+kk, i0+ii]
  int t = threadIdx.x;
  int d0 = blockIdx.y * 128, i0 = blockIdx.x * 128;
  int tx = t & 15, ty = t >> 4;
  float acc[8][8];
#pragma unroll
  for (int r = 0; r < 8; ++r)
#pragma unroll
    for (int c = 0; c < 8; ++c) acc[r][c] = 0.f;

  int akk = (t * 4) & 15, add0 = t >> 2;            // add0 in 0..63, + 64 for 2nd half
  int eb = t * 4;
  int bkk0 = eb >> 7, bii = eb & 127, bkk1 = bkk0 + 8;
  float4 u4 = *(const float4*)&ut[i0 + bii];        // loop-invariant

  for (int k0 = 0; k0 < S; k0 += 16) {
    float4 av0 = *(const float4*)&TF[(d0 + add0) * S + k0 + akk];
    float4 av1 = *(const float4*)&TF[(d0 + add0 + 64) * S + k0 + akk];
    float4 g0 = *(const float4*)&GpT[(k0 + bkk0) * S + i0 + bii];
    float4 g1 = *(const float4*)&GpT[(k0 + bkk1) * S + i0 + bii];
    float v0 = vt[k0 + bkk0], v1 = vt[k0 + bkk1];
    __syncthreads();
    As[akk + 0][add0] = av0.x; As[akk + 1][add0] = av0.y;
    As[akk + 2][add0] = av0.z; As[akk + 3][add0] = av0.w;
    As[akk + 0][add0 + 64] = av1.x; As[akk + 1][add0 + 64] = av1.y;
    As[akk + 2][add0 + 64] = av1.z; As[akk + 3][add0 + 64] = av1.w;
    float4 p0 = make_float4(__expf(g0.x + u4.x + v0), __expf(g0.y + u4.y + v0),
                            __expf(g0.z + u4.z + v0), __expf(g0.w + u4.w + v0));
    float4 p1 = make_float4(__expf(g1.x + u4.x + v1), __expf(g1.y + u4.y + v1),
                            __expf(g1.z + u4.z + v1), __expf(g1.w + u4.w + v1));
    *(float4*)&Bs[bkk0][bii] = p0;
    *(float4*)&Bs[bkk1][bii] = p1;
    __syncthreads();
#pragma unroll
    for (int kk = 0; kk < 16; ++kk) {
      float a[8], b[8];
      *(float4*)&a[0] = *(const float4*)&As[kk][ty * 8];
      *(float4*)&a[4] = *(const float4*)&As[kk][ty * 8 + 4];
      *(float4*)&b[0] = *(const float4*)&Bs[kk][tx * 4];
      *(float4*)&b[4] = *(const float4*)&Bs[kk][64 + tx * 4];
#pragma unroll
      for (int r = 0; r < 8; ++r)
#pragma unroll
        for (int c = 0; c < 8; ++c) acc[r][c] = fmaf(a[r], b[c], acc[r][c]);
    }
  }
#pragma unroll
  for (int r = 0; r < 8; ++r) {
    int d = d0 + ty * 8 + r;
    *(float4*)&RT[d * S + i0 + tx * 4] = *(float4*)&acc[r][0];
    *(float4*)&RT[d * S + i0 + 64 + tx * 4] = *(float4*)&acc[r][4];
  }
}

// dist2[i] += sum_{d in chunk} (qa[i]*QF[d,i] - RT[d,i])^2
__global__ __launch_bounds__(256) void dist2_partial_k(const float* __restrict__ QF,
                                                       const float* __restrict__ RT,
                                                       const float* __restrict__ qa,
                                                       float* __restrict__ dist2) {
  int ib = blockIdx.x & 7, dc = blockIdx.x >> 3;
  int i = ib * 256 + threadIdx.x;
  float qai = qa[i];
  float acc = 0.f;
  int d0 = dc * 256;
  for (int d = d0; d < d0 + 256; ++d) {
    float q = QF[d * S + i];
    float r = RT[d * S + i];
    float x = fmaf(qai, q, -r);
    acc = fmaf(x, x, acc);
  }
  atomicAdd(&dist2[i], acc);
}

__global__ __launch_bounds__(256) void loss_final_k(const float* __restrict__ dist2,
                                                    const float* __restrict__ label,
                                                    float* __restrict__ out) {
  int t = threadIdx.x;
  float acc = 0.f;
#pragma unroll
  for (int k = 0; k < 8; ++k) {
    int i = t + k * 256;
    float d2 = dist2[i];
    float dist = sqrtf(d2);
    float lab = label[i];
    float neg = fmaxf(MARGIN - dist, 0.f);
    acc += 0.5f * lab * d2 + 0.5f * (1.f - lab) * neg * neg;
  }
#pragma unroll
  for (int off = 32; off; off >>= 1) acc += __shfl_xor(acc, off);
  __shared__ float wsum[4];
  int wave = t >> 6, lane = t & 63;
  if (lane == 0) wsum[wave] = acc;
  __syncthreads();
  if (t == 0) out[0] = wsum[0] + wsum[1] + wsum[2] + wsum[3];
}

// ---------------------------------------------------------------------------
extern "C" void kernel_launch(void* const* d_in, const int* in_sizes, int n_in,
                              void* d_out, int out_size, void* d_ws, size_t ws_size,
                              hipStream_t stream) {
  const float* QF  = (const float*)d_in[0];  // [D, m] d-major
  const float* qa  = (const float*)d_in[1];  // [m]
  const float* TF  = (const float*)d_in[2];  // [D, n] d-major
  const float* ta  = (const float*)d_in[3];  // [n]
  const float* lab = (const float*)d_in[4];  // [m]
  float* out = (float*)d_out;

  float* ws = (float*)d_ws;
  float* Gp    = ws;                  // S*S : G' = -2 X^T Y  (reused as RT later)
  float* GpT   = Gp + S * S;          // S*S : G'^T
  float* ut    = GpT + S * S;         // S
  float* vt    = ut + S;              // S
  float* lmu   = vt + S;              // S
  float* lnu   = lmu + S;             // S
  float* dist2 = lnu + S;             // S
  // total: 2*S*S + 5*S floats ~= 33.6 MB

  init_marg_k<<<8, 256, 0, stream>>>(qa, ta, lmu, lnu, vt, dist2);
  colsumsq_k<<<64, 256, 0, stream>>>(TF, vt);  // vt = y2 (== v0 + y2)
  gemm_tn_k<<<dim3(16, 16), 256, 0, stream>>>(QF, TF, Gp, -2.0f);
  transpose_k<<<dim3(32, 32), 256, 0, stream>>>(Gp, GpT);

  for (int it = 0; it < ITERS; ++it) {
    lse_update_k<<<512, 256, 0, stream>>>(Gp, vt, lmu, ut);   // row pass -> ut
    lse_update_k<<<512, 256, 0, stream>>>(GpT, ut, lnu, vt);  // col pass -> vt
  }

  // RT = P @ tf computed transposed: RT[d,i]; aliases Gp (G' dead after last row pass)
  rt_gemm_k<<<dim3(16, 16), 256, 0, stream>>>(TF, GpT, ut, vt, Gp);
  dist2_partial_k<<<64, 256, 0, stream>>>(QF, Gp, qa, dist2);
  loss_final_k<<<1, 256, 0, stream>>>(dist2, lab, out);
}

// Round 2
// 4513.768 us; speedup vs baseline: 1.0036x; 1.0036x over previous
//
#include <hip/hip_runtime.h>
#include <math.h>

#define S 2048
#define MARGIN 0.7f
#define ITERS 500

// ---------------------------------------------------------------------------
// init: log-marginals, zero accumulators
// ---------------------------------------------------------------------------
__global__ __launch_bounds__(256) void init_marg_k(const float* __restrict__ qa,
                                                   const float* __restrict__ ta,
                                                   float* __restrict__ lmu,
                                                   float* __restrict__ lnu,
                                                   float* __restrict__ vt,
                                                   float* __restrict__ dist2) {
  int i = blockIdx.x * 256 + threadIdx.x;
  lmu[i] = __logf(qa[i]);
  lnu[i] = __logf(ta[i]);
  vt[i] = 0.f;     // will accumulate y2 (vt init = v0 + y2 = y2 since v0 = 0)
  dist2[i] = 0.f;
}

// vt[j] += sum_d TF[d,j]^2   (8 j-blocks x 8 d-chunks, atomic combine)
__global__ __launch_bounds__(256) void colsumsq_k(const float* __restrict__ TF,
                                                  float* __restrict__ vt) {
  int jb = blockIdx.x & 7, dc = blockIdx.x >> 3;
  int j = jb * 256 + threadIdx.x;
  int d0 = dc * 256;
  float acc = 0.f;
  for (int d = d0; d < d0 + 256; ++d) {
    float v = TF[d * S + j];
    acc = fmaf(v, v, acc);
  }
  atomicAdd(&vt[j], acc);
}

// ---------------------------------------------------------------------------
// C[i,j] = alpha * sum_k A[k*S+i] * B[k*S+j]   (128x128 tile, BK=16, 8x8/thread)
// ---------------------------------------------------------------------------
__global__ __launch_bounds__(256) void gemm_tn_k(const float* __restrict__ A,
                                                 const float* __restrict__ B,
                                                 float* __restrict__ C, float alpha) {
  __shared__ float As[16][128];
  __shared__ float Bs[16][128];
  int t = threadIdx.x;
  int i0 = blockIdx.y * 128, j0 = blockIdx.x * 128;
  int tx = t & 15, ty = t >> 4;
  float acc[8][8];
#pragma unroll
  for (int r = 0; r < 8; ++r)
#pragma unroll
    for (int c = 0; c < 8; ++c) acc[r][c] = 0.f;

  int e = t * 4;
  int dd0 = e >> 7, ii = e & 127;
  int dd1 = dd0 + 8;
  for (int k0 = 0; k0 < S; k0 += 16) {
    float4 a0 = *(const float4*)&A[(k0 + dd0) * S + i0 + ii];
    float4 b0 = *(const float4*)&B[(k0 + dd0) * S + j0 + ii];
    float4 a1 = *(const float4*)&A[(k0 + dd1) * S + i0 + ii];
    float4 b1 = *(const float4*)&B[(k0 + dd1) * S + j0 + ii];
    __syncthreads();
    *(float4*)&As[dd0][ii] = a0; *(float4*)&Bs[dd0][ii] = b0;
    *(float4*)&As[dd1][ii] = a1; *(float4*)&Bs[dd1][ii] = b1;
    __syncthreads();
#pragma unroll
    for (int kk = 0; kk < 16; ++kk) {
      float a[8], b[8];
      *(float4*)&a[0] = *(const float4*)&As[kk][ty * 8];
      *(float4*)&a[4] = *(const float4*)&As[kk][ty * 8 + 4];
      *(float4*)&b[0] = *(const float4*)&Bs[kk][tx * 4];
      *(float4*)&b[4] = *(const float4*)&Bs[kk][64 + tx * 4];
#pragma unroll
      for (int r = 0; r < 8; ++r)
#pragma unroll
        for (int c = 0; c < 8; ++c) acc[r][c] = fmaf(a[r], b[c], acc[r][c]);
    }
  }
#pragma unroll
  for (int r = 0; r < 8; ++r) {
    int i = i0 + ty * 8 + r;
    float4 o0 = make_float4(acc[r][0] * alpha, acc[r][1] * alpha, acc[r][2] * alpha, acc[r][3] * alpha);
    float4 o1 = make_float4(acc[r][4] * alpha, acc[r][5] * alpha, acc[r][6] * alpha, acc[r][7] * alpha);
    *(float4*)&C[i * S + j0 + tx * 4] = o0;
    *(float4*)&C[i * S + j0 + 64 + tx * 4] = o1;
  }
}

// ---------------------------------------------------------------------------
// out[j*S+i] = in[i*S+j]  (64x64 LDS tiles)
// ---------------------------------------------------------------------------
__global__ __launch_bounds__(256) void transpose_k(const float* __restrict__ in,
                                                   float* __restrict__ out) {
  __shared__ float tile[64][65];
  int i0 = blockIdx.y * 64, j0 = blockIdx.x * 64;
  int tx = threadIdx.x & 63, ty = threadIdx.x >> 6;  // ty 0..3
#pragma unroll
  for (int r = 0; r < 16; ++r) {
    int row = r * 4 + ty;
    tile[row][tx] = in[(i0 + row) * S + j0 + tx];
  }
  __syncthreads();
#pragma unroll
  for (int r = 0; r < 16; ++r) {
    int row = r * 4 + ty;
    out[(j0 + row) * S + i0 + tx] = tile[tx][row];
  }
}

// ---------------------------------------------------------------------------
// outPot[r] = logMarg[r] - LSE_c( G[r*S+c] + inPot[c] )
// ONE BLOCK PER ROW: 4 waves cooperate, 8 floats/lane held in registers.
// grid=2048, block=256 -> 8 blocks/CU = 32 waves/CU (full occupancy), vs the
// previous wave-per-row layout (512 blocks, 2 blocks/CU, 8 waves/CU) which
// was latency-bound at ~4.3 TB/s effective.
// ---------------------------------------------------------------------------
__global__ __launch_bounds__(256) void lse_update_k(const float* __restrict__ G,
                                                    const float* __restrict__ inPot,
                                                    const float* __restrict__ logMarg,
                                                    float* __restrict__ outPot) {
  __shared__ float red[8];
  int t = threadIdx.x;
  int row = blockIdx.x;
  const float* g = G + (size_t)row * S;
  int idx = t * 8;
  float4 g0 = *(const float4*)&g[idx];
  float4 g1 = *(const float4*)&g[idx + 4];
  float4 p0 = *(const float4*)&inPot[idx];
  float4 p1 = *(const float4*)&inPot[idx + 4];
  float v0 = g0.x + p0.x, v1 = g0.y + p0.y, v2 = g0.z + p0.z, v3 = g0.w + p0.w;
  float v4 = g1.x + p1.x, v5 = g1.y + p1.y, v6 = g1.z + p1.z, v7 = g1.w + p1.w;
  float mx = fmaxf(fmaxf(fmaxf(v0, v1), fmaxf(v2, v3)),
                   fmaxf(fmaxf(v4, v5), fmaxf(v6, v7)));
#pragma unroll
  for (int off = 32; off; off >>= 1) mx = fmaxf(mx, __shfl_xor(mx, off));
  int wave = t >> 6, lane = t & 63;
  if (lane == 0) red[wave] = mx;
  __syncthreads();
  mx = fmaxf(fmaxf(red[0], red[1]), fmaxf(red[2], red[3]));
  float s = __expf(v0 - mx) + __expf(v1 - mx) + __expf(v2 - mx) + __expf(v3 - mx) +
            __expf(v4 - mx) + __expf(v5 - mx) + __expf(v6 - mx) + __expf(v7 - mx);
#pragma unroll
  for (int off = 32; off; off >>= 1) s += __shfl_xor(s, off);
  if (lane == 0) red[4 + wave] = s;
  __syncthreads();
  if (t == 0) {
    s = red[4] + red[5] + red[6] + red[7];
    outPot[row] = logMarg[row] - (mx + __logf(s));
  }
}

// ---------------------------------------------------------------------------
// RT[d,i] = sum_j TF[d,j] * exp( GpT[j*S+i] + ut[i] + vt[j] )
// (C = A * P^T with P^T generated on the fly into LDS; 128x128 tile, BK=16)
// ---------------------------------------------------------------------------
__global__ __launch_bounds__(256) void rt_gemm_k(const float* __restrict__ TF,
                                                 const float* __restrict__ GpT,
                                                 const float* __restrict__ ut,
                                                 const float* __restrict__ vt,
                                                 float* __restrict__ RT) {
  __shared__ float As[16][128];  // As[kk][dd] = TF[(d0+dd)*S + k0+kk]
  __shared__ float Bs[16][128];  // Bs[kk][ii] = P^T[k0+kk, i0+ii]
  int t = threadIdx.x;
  int d0 = blockIdx.y * 128, i0 = blockIdx.x * 128;
  int tx = t & 15, ty = t >> 4;
  float acc[8][8];
#pragma unroll
  for (int r = 0; r < 8; ++r)
#pragma unroll
    for (int c = 0; c < 8; ++c) acc[r][c] = 0.f;

  int akk = (t * 4) & 15, add0 = t >> 2;            // add0 in 0..63, + 64 for 2nd half
  int eb = t * 4;
  int bkk0 = eb >> 7, bii = eb & 127, bkk1 = bkk0 + 8;
  float4 u4 = *(const float4*)&ut[i0 + bii];        // loop-invariant

  for (int k0 = 0; k0 < S; k0 += 16) {
    float4 av0 = *(const float4*)&TF[(d0 + add0) * S + k0 + akk];
    float4 av1 = *(const float4*)&TF[(d0 + add0 + 64) * S + k0 + akk];
    float4 g0 = *(const float4*)&GpT[(k0 + bkk0) * S + i0 + bii];
    float4 g1 = *(const float4*)&GpT[(k0 + bkk1) * S + i0 + bii];
    float v0 = vt[k0 + bkk0], v1 = vt[k0 + bkk1];
    __syncthreads();
    As[akk + 0][add0] = av0.x; As[akk + 1][add0] = av0.y;
    As[akk + 2][add0] = av0.z; As[akk + 3][add0] = av0.w;
    As[akk + 0][add0 + 64] = av1.x; As[akk + 1][add0 + 64] = av1.y;
    As[akk + 2][add0 + 64] = av1.z; As[akk + 3][add0 + 64] = av1.w;
    float4 p0 = make_float4(__expf(g0.x + u4.x + v0), __expf(g0.y + u4.y + v0),
                            __expf(g0.z + u4.z + v0), __expf(g0.w + u4.w + v0));
    float4 p1 = make_float4(__expf(g1.x + u4.x + v1), __expf(g1.y + u4.y + v1),
                            __expf(g1.z + u4.z + v1), __expf(g1.w + u4.w + v1));
    *(float4*)&Bs[bkk0][bii] = p0;
    *(float4*)&Bs[bkk1][bii] = p1;
    __syncthreads();
#pragma unroll
    for (int kk = 0; kk < 16; ++kk) {
      float a[8], b[8];
      *(float4*)&a[0] = *(const float4*)&As[kk][ty * 8];
      *(float4*)&a[4] = *(const float4*)&As[kk][ty * 8 + 4];
      *(float4*)&b[0] = *(const float4*)&Bs[kk][tx * 4];
      *(float4*)&b[4] = *(const float4*)&Bs[kk][64 + tx * 4];
#pragma unroll
      for (int r = 0; r < 8; ++r)
#pragma unroll
        for (int c = 0; c < 8; ++c) acc[r][c] = fmaf(a[r], b[c], acc[r][c]);
    }
  }
#pragma unroll
  for (int r = 0; r < 8; ++r) {
    int d = d0 + ty * 8 + r;
    *(float4*)&RT[d * S + i0 + tx * 4] = *(float4*)&acc[r][0];
    *(float4*)&RT[d * S + i0 + 64 + tx * 4] = *(float4*)&acc[r][4];
  }
}

// dist2[i] += sum_{d in chunk} (qa[i]*QF[d,i] - RT[d,i])^2
__global__ __launch_bounds__(256) void dist2_partial_k(const float* __restrict__ QF,
                                                       const float* __restrict__ RT,
                                                       const float* __restrict__ qa,
                                                       float* __restrict__ dist2) {
  int ib = blockIdx.x & 7, dc = blockIdx.x >> 3;
  int i = ib * 256 + threadIdx.x;
  float qai = qa[i];
  float acc = 0.f;
  int d0 = dc * 256;
  for (int d = d0; d < d0 + 256; ++d) {
    float q = QF[d * S + i];
    float r = RT[d * S + i];
    float x = fmaf(qai, q, -r);
    acc = fmaf(x, x, acc);
  }
  atomicAdd(&dist2[i], acc);
}

__global__ __launch_bounds__(256) void loss_final_k(const float* __restrict__ dist2,
                                                    const float* __restrict__ label,
                                                    float* __restrict__ out) {
  int t = threadIdx.x;
  float acc = 0.f;
#pragma unroll
  for (int k = 0; k < 8; ++k) {
    int i = t + k * 256;
    float d2 = dist2[i];
    float dist = sqrtf(d2);
    float lab = label[i];
    float neg = fmaxf(MARGIN - dist, 0.f);
    acc += 0.5f * lab * d2 + 0.5f * (1.f - lab) * neg * neg;
  }
#pragma unroll
  for (int off = 32; off; off >>= 1) acc += __shfl_xor(acc, off);
  __shared__ float wsum[4];
  int wave = t >> 6, lane = t & 63;
  if (lane == 0) wsum[wave] = acc;
  __syncthreads();
  if (t == 0) out[0] = wsum[0] + wsum[1] + wsum[2] + wsum[3];
}

// ---------------------------------------------------------------------------
extern "C" void kernel_launch(void* const* d_in, const int* in_sizes, int n_in,
                              void* d_out, int out_size, void* d_ws, size_t ws_size,
                              hipStream_t stream) {
  const float* QF  = (const float*)d_in[0];  // [D, m] d-major
  const float* qa  = (const float*)d_in[1];  // [m]
  const float* TF  = (const float*)d_in[2];  // [D, n] d-major
  const float* ta  = (const float*)d_in[3];  // [n]
  const float* lab = (const float*)d_in[4];  // [m]
  float* out = (float*)d_out;

  float* ws = (float*)d_ws;
  float* Gp    = ws;                  // S*S : G' = -2 X^T Y  (reused as RT later)
  float* GpT   = Gp + S * S;          // S*S : G'^T
  float* ut    = GpT + S * S;         // S
  float* vt    = ut + S;              // S
  float* lmu   = vt + S;              // S
  float* lnu   = lmu + S;             // S
  float* dist2 = lnu + S;             // S
  // total: 2*S*S + 5*S floats ~= 33.6 MB

  init_marg_k<<<8, 256, 0, stream>>>(qa, ta, lmu, lnu, vt, dist2);
  colsumsq_k<<<64, 256, 0, stream>>>(TF, vt);  // vt = y2 (== v0 + y2)
  gemm_tn_k<<<dim3(16, 16), 256, 0, stream>>>(QF, TF, Gp, -2.0f);
  transpose_k<<<dim3(32, 32), 256, 0, stream>>>(Gp, GpT);

  for (int it = 0; it < ITERS; ++it) {
    lse_update_k<<<2048, 256, 0, stream>>>(Gp, vt, lmu, ut);   // row pass -> ut
    lse_update_k<<<2048, 256, 0, stream>>>(GpT, ut, lnu, vt);  // col pass -> vt
  }

  // RT = P @ tf computed transposed: RT[d,i]; aliases Gp (G' dead after last row pass)
  rt_gemm_k<<<dim3(16, 16), 256, 0, stream>>>(TF, GpT, ut, vt, Gp);
  dist2_partial_k<<<64, 256, 0, stream>>>(QF, Gp, qa, dist2);
  loss_final_k<<<1, 256, 0, stream>>>(dist2, lab, out);
}